// Round 10
// baseline (1409.435 us; speedup 1.0000x reference)
//
#include <hip/hip_runtime.h>
#include <math.h>

typedef unsigned long long u64;
typedef unsigned int u32;

// key = (f32 bits of priority << 23) | edge index.
// Order-isomorphic to stable argsort rank: p >= 0 -> f32 bits value-monotone;
// index breaks ties exactly like stable argsort. E < 2^23.
__device__ __forceinline__ u64 mkkey(float p, int e) {
    return ((u64)__float_as_uint(p) << 23) | (unsigned)e;
}
__device__ __forceinline__ u64 umax64(u64 a, u64 b) { return a > b ? a : b; }

__global__ void k_sentinel(float* out, float v) {
    if (threadIdx.x == 0 && blockIdx.x == 0) out[0] = v;
}

__global__ void k_zero16(uint4* __restrict__ p, int n) {
    int i = blockIdx.x * blockDim.x + threadIdx.x;
    if (i < n) p[i] = make_uint4(0, 0, 0, 0);
}

__global__ void k_copyW(u64* __restrict__ dst, const u64* __restrict__ src, int n) {
    int i = blockIdx.x * blockDim.x + threadIdx.x;
    if (i < n) dst[i] = src[i];
}

// ---------------- batched (4 edges/thread) sweeps: 8 outstanding gathers ----

// iter1: vert = max(vert, key) at both endpoints; read-filter (vert monotone,
// stale reads only smaller -> skip conservative-correct).
__global__ void k_scatter1_b4(const int4* __restrict__ e4, const float4* __restrict__ p4,
                              u64* __restrict__ vert, int nq) {
    int t = blockIdx.x * blockDim.x + threadIdx.x;
    if (t >= nq) return;
    int4 ea = e4[2 * t], eb = e4[2 * t + 1];
    float4 p = p4[t];
    int e = 4 * t;
    u64 k0 = mkkey(p.x, e), k1 = mkkey(p.y, e + 1);
    u64 k2 = mkkey(p.z, e + 2), k3 = mkkey(p.w, e + 3);
    u64 a0 = vert[ea.x], b0 = vert[ea.y], a1 = vert[ea.z], b1 = vert[ea.w];
    u64 a2 = vert[eb.x], b2 = vert[eb.y], a3 = vert[eb.z], b3 = vert[eb.w];
    if (k0 > a0) atomicMax(&vert[ea.x], k0);
    if (k0 > b0) atomicMax(&vert[ea.y], k0);
    if (k1 > a1) atomicMax(&vert[ea.z], k1);
    if (k1 > b1) atomicMax(&vert[ea.w], k1);
    if (k2 > a2) atomicMax(&vert[eb.x], k2);
    if (k2 > b2) atomicMax(&vert[eb.y], k2);
    if (k3 > a3) atomicMax(&vert[eb.z], k3);
    if (k3 > b3) atomicMax(&vert[eb.w], k3);
}

// Jacobi step (vdst pre-copied from vsrc): er=max(vsrc[x],vsrc[y]); max into vdst.
__global__ void k_fused_b4(const int4* __restrict__ e4, const u64* __restrict__ vsrc,
                           u64* __restrict__ vdst, int nq) {
    int t = blockIdx.x * blockDim.x + threadIdx.x;
    if (t >= nq) return;
    int4 ea = e4[2 * t], eb = e4[2 * t + 1];
    u64 a0 = vsrc[ea.x], b0 = vsrc[ea.y], a1 = vsrc[ea.z], b1 = vsrc[ea.w];
    u64 a2 = vsrc[eb.x], b2 = vsrc[eb.y], a3 = vsrc[eb.z], b3 = vsrc[eb.w];
    u64 m0 = umax64(a0, b0), m1 = umax64(a1, b1);
    u64 m2 = umax64(a2, b2), m3 = umax64(a3, b3);
    if (m0 > a0) atomicMax(&vdst[ea.x], m0);
    if (m0 > b0) atomicMax(&vdst[ea.y], m0);
    if (m1 > a1) atomicMax(&vdst[ea.z], m1);
    if (m1 > b1) atomicMax(&vdst[ea.w], m1);
    if (m2 > a2) atomicMax(&vdst[eb.x], m2);
    if (m2 > b2) atomicMax(&vdst[eb.y], m2);
    if (m3 > a3) atomicMax(&vdst[eb.z], m3);
    if (m3 > b3) atomicMax(&vdst[eb.w], m3);
}

// final gather + cand test; cand packed 4 bytes -> one u32 store.
// cand edges form a matching (unique keys, strict local maxima) -> plain stores.
__global__ void k_cand_b4(const int4* __restrict__ e4, const float4* __restrict__ p4,
                          const u64* __restrict__ vert, unsigned char* __restrict__ flags,
                          u32* __restrict__ cand4, int nq) {
    int t = blockIdx.x * blockDim.x + threadIdx.x;
    if (t >= nq) return;
    int4 ea = e4[2 * t], eb = e4[2 * t + 1];
    float4 p = p4[t];
    int e = 4 * t;
    u64 a0 = vert[ea.x], b0 = vert[ea.y], a1 = vert[ea.z], b1 = vert[ea.w];
    u64 a2 = vert[eb.x], b2 = vert[eb.y], a3 = vert[eb.z], b3 = vert[eb.w];
    u32 cw = 0;
    if ((umax64(a0, b0) == mkkey(p.x, e)) && (p.x > 0.0f)) {
        cw |= 1u;        flags[ea.x] = 3; if (ea.y != ea.x) flags[ea.y] = 2;
    }
    if ((umax64(a1, b1) == mkkey(p.y, e + 1)) && (p.y > 0.0f)) {
        cw |= 0x100u;    flags[ea.z] = 3; if (ea.w != ea.z) flags[ea.w] = 2;
    }
    if ((umax64(a2, b2) == mkkey(p.z, e + 2)) && (p.z > 0.0f)) {
        cw |= 0x10000u;  flags[eb.x] = 3; if (eb.y != eb.x) flags[eb.y] = 2;
    }
    if ((umax64(a3, b3) == mkkey(p.w, e + 3)) && (p.w > 0.0f)) {
        cw |= 0x1000000u; flags[eb.z] = 3; if (eb.w != eb.z) flags[eb.w] = 2;
    }
    cand4[t] = cw;
}

// add round 1 into pack lo16: ec = A[x]+A[y]
__global__ void k_conn1_b4(const int4* __restrict__ e4, const unsigned char* __restrict__ flags,
                           u32* __restrict__ pack, int nq) {
    int t = blockIdx.x * blockDim.x + threadIdx.x;
    if (t >= nq) return;
    int4 ea = e4[2 * t], eb = e4[2 * t + 1];
    u32 x0 = flags[ea.x] & 1, y0 = flags[ea.y] & 1;
    u32 x1 = flags[ea.z] & 1, y1 = flags[ea.w] & 1;
    u32 x2 = flags[eb.x] & 1, y2 = flags[eb.y] & 1;
    u32 x3 = flags[eb.z] & 1, y3 = flags[eb.w] & 1;
    u32 e0 = x0 + y0, e1 = x1 + y1, e2 = x2 + y2, e3 = x3 + y3;
    if (e0) { atomicAdd(&pack[ea.x], e0); atomicAdd(&pack[ea.y], e0); }
    if (e1) { atomicAdd(&pack[ea.z], e1); atomicAdd(&pack[ea.w], e1); }
    if (e2) { atomicAdd(&pack[eb.x], e2); atomicAdd(&pack[eb.y], e2); }
    if (e3) { atomicAdd(&pack[eb.z], e3); atomicAdd(&pack[eb.w], e3); }
}

// add round 2 into pack hi16; set-0 applied at read via markC bit (bit1).
// lo16 stable during this kernel (only <<16 adds; sums << 2^16, no carry).
__global__ void k_conn2_b4(const int4* __restrict__ e4, const unsigned char* __restrict__ flags,
                           u32* __restrict__ pack, int nq) {
    int t = blockIdx.x * blockDim.x + threadIdx.x;
    if (t >= nq) return;
    int4 ea = e4[2 * t], eb = e4[2 * t + 1];
#define F2(gx, px) ((gx & 2) ? 0u : ((u32)(gx & 1) + ((px) & 0xFFFFu)))
    unsigned char g0x = flags[ea.x], g0y = flags[ea.y];
    unsigned char g1x = flags[ea.z], g1y = flags[ea.w];
    unsigned char g2x = flags[eb.x], g2y = flags[eb.y];
    unsigned char g3x = flags[eb.z], g3y = flags[eb.w];
    u32 p0x = pack[ea.x], p0y = pack[ea.y], p1x = pack[ea.z], p1y = pack[ea.w];
    u32 p2x = pack[eb.x], p2y = pack[eb.y], p3x = pack[eb.z], p3y = pack[eb.w];
    u32 e0 = F2(g0x, p0x) + F2(g0y, p0y);
    u32 e1 = F2(g1x, p1x) + F2(g1y, p1y);
    u32 e2 = F2(g2x, p2x) + F2(g2y, p2y);
    u32 e3 = F2(g3x, p3x) + F2(g3y, p3y);
    if (e0) { atomicAdd(&pack[ea.x], e0 << 16); atomicAdd(&pack[ea.y], e0 << 16); }
    if (e1) { atomicAdd(&pack[ea.z], e1 << 16); atomicAdd(&pack[ea.w], e1 << 16); }
    if (e2) { atomicAdd(&pack[eb.x], e2 << 16); atomicAdd(&pack[eb.y], e2 << 16); }
    if (e3) { atomicAdd(&pack[eb.z], e3 << 16); atomicAdd(&pack[eb.w], e3 << 16); }
#undef F2
}

// ---------------- scalar tail variants (edges [off, E)) ---------------------

__global__ void k_scatter1_s(const int2* __restrict__ edges, const float* __restrict__ pri,
                             u64* __restrict__ vert, int E, int off) {
    int e = off + blockIdx.x * blockDim.x + threadIdx.x;
    if (e >= E) return;
    u64 k = mkkey(pri[e], e);
    int2 ed = edges[e];
    u64 a = vert[ed.x], b = vert[ed.y];
    if (k > a) atomicMax(&vert[ed.x], k);
    if (k > b) atomicMax(&vert[ed.y], k);
}
__global__ void k_fused_s(const int2* __restrict__ edges, const u64* __restrict__ vsrc,
                          u64* __restrict__ vdst, int E, int off) {
    int e = off + blockIdx.x * blockDim.x + threadIdx.x;
    if (e >= E) return;
    int2 ed = edges[e];
    u64 a = vsrc[ed.x], b = vsrc[ed.y];
    u64 er = umax64(a, b);
    if (er > a) atomicMax(&vdst[ed.x], er);
    if (er > b) atomicMax(&vdst[ed.y], er);
}
__global__ void k_cand_s(const int2* __restrict__ edges, const float* __restrict__ pri,
                         const u64* __restrict__ vert, unsigned char* __restrict__ flags,
                         unsigned char* __restrict__ cand, int E, int off) {
    int e = off + blockIdx.x * blockDim.x + threadIdx.x;
    if (e >= E) return;
    int2 ed = edges[e];
    u64 er = umax64(vert[ed.x], vert[ed.y]);
    float p = pri[e];
    bool c = (er == mkkey(p, e)) && (p > 0.0f);
    cand[e] = c ? 1 : 0;
    if (c) { flags[ed.x] = 3; if (ed.y != ed.x) flags[ed.y] = 2; }
}
__global__ void k_conn1_s(const int2* __restrict__ edges, const unsigned char* __restrict__ flags,
                          u32* __restrict__ pack, int E, int off) {
    int e = off + blockIdx.x * blockDim.x + threadIdx.x;
    if (e >= E) return;
    int2 ed = edges[e];
    u32 ec = (u32)(flags[ed.x] & 1) + (u32)(flags[ed.y] & 1);
    if (ec) { atomicAdd(&pack[ed.x], ec); atomicAdd(&pack[ed.y], ec); }
}
__global__ void k_conn2_s(const int2* __restrict__ edges, const unsigned char* __restrict__ flags,
                          u32* __restrict__ pack, int E, int off) {
    int e = off + blockIdx.x * blockDim.x + threadIdx.x;
    if (e >= E) return;
    int2 ed = edges[e];
    unsigned char gx = flags[ed.x], gy = flags[ed.y];
    u32 fx = (gx & 2) ? 0u : ((u32)(gx & 1) + (pack[ed.x] & 0xFFFFu));
    u32 fy = (gy & 2) ? 0u : ((u32)(gy & 1) + (pack[ed.y] & 0xFFFFu));
    u32 ec = fx + fy;
    if (ec) { atomicAdd(&pack[ed.x], ec << 16); atomicAdd(&pack[ed.y], ec << 16); }
}

// collapse: memoized cand early-out; final conn[e1]=(markC?0:A+lo)+hi; if <=2:
// repl[e1]=e0+1, vout[e0]=f32 midpoint (matching -> race-free).
__global__ void k_collapse(const int2* __restrict__ edges, const unsigned char* __restrict__ cand,
                           const unsigned char* __restrict__ flags,
                           const u32* __restrict__ pack, const float* __restrict__ vin,
                           int* __restrict__ repl, float* __restrict__ vout, int E) {
    int e = blockIdx.x * blockDim.x + threadIdx.x;
    if (e >= E) return;
    if (!cand[e]) return;
    int2 ed = edges[e];
    unsigned char gy = flags[ed.y];
    u32 py = pack[ed.y];
    u32 fy = (gy & 2) ? 0u : ((u32)(gy & 1) + (py & 0xFFFFu));
    u32 total = fy + (py >> 16);
    if (total <= 2) {
        repl[ed.y] = ed.x + 1;
        size_t bx = (size_t)ed.x * 3, by = (size_t)ed.y * 3;
#pragma unroll
        for (int j = 0; j < 3; ++j)
            vout[bx + j] = 0.5f * (vin[bx + j] + vin[by + j]);
    }
}

__global__ void k_faces(const int* __restrict__ faces, const int* __restrict__ repl,
                        float* __restrict__ fout, int F) {
    int i = blockIdx.x * blockDim.x + threadIdx.x;
    if (i >= F) return;
    size_t b = (size_t)i * 3;
    int a0 = faces[b + 0], a1 = faces[b + 1], a2 = faces[b + 2];
    int r0 = repl[a0]; if (r0) a0 = r0 - 1;
    int r1 = repl[a1]; if (r1) a1 = r1 - 1;
    int r2 = repl[a2]; if (r2) a2 = r2 - 1;
    if (a0 == a1 || a1 == a2 || a0 == a2) { a0 = 0; a1 = 0; a2 = 0; }
    fout[b + 0] = (float)a0;
    fout[b + 1] = (float)a1;
    fout[b + 2] = (float)a2;
}

extern "C" void kernel_launch(void* const* d_in, const int* in_sizes, int n_in,
                              void* d_out, int out_size, void* d_ws, size_t ws_size,
                              hipStream_t stream) {
    const int V = in_sizes[0] / 3;
    const int F = in_sizes[1] / 3;
    const int E = in_sizes[3];

    const float* vin  = (const float*)d_in[0];
    const int* faces  = (const int*)d_in[1];
    const int2* edges = (const int2*)d_in[2];
    const float* pri  = (const float*)d_in[3];
    const int4* e4    = (const int4*)d_in[2];
    const float4* p4  = (const float4*)d_in[3];

    float* vout = (float*)d_out;                 // f32 vertices [0, 3V)
    float* fout = vout + (size_t)V * 3;          // f32 face ids [3V, 3V+3F)

    // ws (~56MB): zero span [vertA(16M) flags(2M) pack(8M) repl(8M)]
    //             then vertB(16M) cand(6M)
    char* ws = (char*)d_ws;
    size_t off = 0;
    auto alloc = [&](size_t n) -> void* {
        void* p = ws + off;
        off = (off + n + 255) & ~(size_t)255;
        return p;
    };
    u64* vertA           = (u64*)alloc((size_t)V * 8);
    unsigned char* flags = (unsigned char*)alloc((size_t)V);
    u32* pack            = (u32*)alloc((size_t)V * 4);
    int* repl            = (int*)alloc((size_t)V * 4);
    size_t zero_bytes = off;
    u64* vertB           = (u64*)alloc((size_t)V * 8);
    unsigned char* cand  = (unsigned char*)alloc((size_t)E + 4);
    size_t needed = off;

    const int TB = 256;
    if (ws_size > 0 && ws_size < needed) {
        k_sentinel<<<1, 64, 0, stream>>>(vout, ldexpf(1.0f, (int)(ws_size >> 23)));
        return;
    }

    const int nq = E >> 2, rem = E & 3, tail = nq << 2;
    const int gQ = (nq + TB - 1) / TB;
    const int gT = rem ? 1 : 0;                 // rem < 4 -> one tiny block
    const int gE = (E + TB - 1) / TB;
    const int gF = (F + TB - 1) / TB;
    const int gW = (V + TB - 1) / TB;
    const int nZ = (int)(zero_bytes / 16);
    const int gZ = (nZ + TB - 1) / TB;

    k_zero16<<<gZ, TB, 0, stream>>>((uint4*)ws, nZ);
    hipMemcpyAsync(d_out, d_in[0], (size_t)V * 3 * sizeof(float),
                   hipMemcpyDeviceToDevice, stream);

    k_scatter1_b4<<<gQ, TB, 0, stream>>>(e4, p4, vertA, nq);
    if (gT) k_scatter1_s<<<gT, TB, 0, stream>>>(edges, pri, vertA, E, tail);

    k_copyW<<<gW, TB, 0, stream>>>(vertB, vertA, V);
    k_fused_b4<<<gQ, TB, 0, stream>>>(e4, vertA, vertB, nq);
    if (gT) k_fused_s<<<gT, TB, 0, stream>>>(edges, vertA, vertB, E, tail);

    k_copyW<<<gW, TB, 0, stream>>>(vertA, vertB, V);
    k_fused_b4<<<gQ, TB, 0, stream>>>(e4, vertB, vertA, nq);
    if (gT) k_fused_s<<<gT, TB, 0, stream>>>(edges, vertB, vertA, E, tail);

    k_cand_b4<<<gQ, TB, 0, stream>>>(e4, p4, vertA, flags, (u32*)cand, nq);
    if (gT) k_cand_s<<<gT, TB, 0, stream>>>(edges, pri, vertA, flags, cand, E, tail);

    k_conn1_b4<<<gQ, TB, 0, stream>>>(e4, flags, pack, nq);
    if (gT) k_conn1_s<<<gT, TB, 0, stream>>>(edges, flags, pack, E, tail);

    k_conn2_b4<<<gQ, TB, 0, stream>>>(e4, flags, pack, nq);
    if (gT) k_conn2_s<<<gT, TB, 0, stream>>>(edges, flags, pack, E, tail);

    k_collapse<<<gE, TB, 0, stream>>>(edges, cand, flags, pack, vin,
                                      repl, vout, E);
    k_faces<<<gF, TB, 0, stream>>>(faces, repl, fout, F);
}